// Round 1
// baseline (281.982 us; speedup 1.0000x reference)
//
#include <hip/hip_runtime.h>

// PerformerAttention: B=4 H=16 S=4096 D=64, fp32.
//   q = relu(Q)+eps; k = (relu(K)+eps)*mask
//   kv[bh][d][e] = sum_s k[s][d]*v[s][e];  ksum[bh][d] = sum_s k[s][d]
//   out[s][e] = (sum_d q[s][d]*kv[d][e]) / (sum_d q[s][d]*ksum[d])
//
// R5: pa_kv_partial was latency-bound (VALU 28%, HBM 17%, 0 bank conflicts,
// occupancy 16%) with a depth-1 prefetch: loads issued one ~1100-cyc compute
// phase before a drain-to-zero wait -> per-round stall = latency - phase.
// This round: depth-2 pipeline, wave-private (no barriers):
//   * V tiles: global_load_lds (16B) into a 3-deep rotating LDS ring
//     (no VGPR staging; the old layout is already base + lane*16).
//   * K tiles: register path (needs relu/eps/mask/ksum pre-stage) with two
//     alternating register sets A/B.
//   * tile t+2 issued during tile t; counted s_waitcnt vmcnt(8) keeps
//     2 tiles x 4 VMEM instrs in flight continuously. Drains happen in
//     whole 4-instr groups, so counts tolerate intra-group reordering;
//     prologue group order pinned with empty-asm fences.
// pa_reduce / pa_out / launcher unchanged (attribution).

namespace {
constexpr int kB = 4, kH = 16, kS = 4096, kD = 64;
constexpr int kBH = kB * kH;
constexpr float kEps = 0.001f;

constexpr int KVSZ = kD * kD;     // 4096 floats
constexpr int SEG  = KVSZ + kD;   // 4160 floats per partial segment (kv + ksum)
constexpr int F4PS = SEG / 4;     // 1040 float4 per segment
}

// async global->LDS, 16 B per lane; LDS dest = wave-uniform base + lane*16
__device__ __forceinline__ void async_cp16(const float* g, float* l) {
  __builtin_amdgcn_global_load_lds(
      (const __attribute__((address_space(1))) void*)g,
      (__attribute__((address_space(3))) void*)l, 16, 0, 0);
}

// ---------------- Pass 1: partial kv + ksum, one segment per BLOCK ---------
__global__ __launch_bounds__(256, 2)   // (256,4) caused a 64-VGPR spill disaster; do not re-add
void pa_kv_partial(const float* __restrict__ key, const float* __restrict__ value,
                   const float* __restrict__ mask, float* __restrict__ P, int ch1) {
  __shared__ float smemV[3 * 2048];  // 3-deep V ring x 4 waves x 512 (8 rows x 64); combine reuses [0..4096)
  __shared__ float smemK[4 * 512];   // per-wave masked/relu'd K tile, single-buffered
  __shared__ float msk[512];         // block's mask slice (so loop vmcnt counts stay exact)
  __shared__ float ksm[256];         // per-wave ksum staging

  const int tid  = threadIdx.x;
  const int wid  = tid >> 6;
  const int lane = tid & 63;

  const int bh    = blockIdx.x / ch1;
  const int chunk = blockIdx.x - bh * ch1;
  const int b     = bh >> 4;                 // kH = 16
  const int rows  = kS / ch1;
  const int s0    = chunk * rows;
  const int tiles = rows >> 5;               // 8-row tiles per wave, 4 waves (8 @ CH1=16)

  const float* kg = key   + (size_t)bh * kS * kD;
  const float* vg = value + (size_t)bh * kS * kD;
  const float* mb = mask  + (size_t)b * kS;

  for (int i = tid; i < rows; i += 256) msk[i] = mb[s0 + i];
  __syncthreads();

  float* ksT = smemK + wid * 512;            // wave-private K tile
  float* v0b = smemV + wid * 512;            // V ring: tile t (read)
  float* v1b = smemV + 2048 + wid * 512;     //         tile t+1
  float* v2b = smemV + 4096 + wid * 512;     //         tile t+2 (stage target)

  const int lrow = lane >> 4;                // 0..3   (load map)
  const int lcol = (lane & 15) << 2;         // 0..60
  const int ti   = lane >> 3;                // 0..7   (compute map: d rows 8*ti..)
  const int tj   = lane & 7;                 // 0..7   (e cols 8*tj..)

  float acc[8][8];
#pragma unroll
  for (int i = 0; i < 8; ++i)
#pragma unroll
    for (int j = 0; j < 8; ++j) acc[i][j] = 0.f;
  float4 ksacc = make_float4(0.f, 0.f, 0.f, 0.f);

  // ---- prologue: stage tiles 0,1 (V->LDS ring, K->reg sets A,B) ----
  const int r0 = wid * 8;                    // wave's tile-0 row offset in chunk
  float4 kqA0, kqA1, kqB0, kqB1;
  float mA0, mA1, mB0, mB1;

  async_cp16(vg + (size_t)(s0 + r0 + lrow) * kD + lcol, v0b);
  async_cp16(vg + (size_t)(s0 + r0 + 4 + lrow) * kD + lcol, v0b + 256);
  kqA0 = *(const float4*)(kg + (size_t)(s0 + r0 + lrow) * kD + lcol);
  kqA1 = *(const float4*)(kg + (size_t)(s0 + r0 + 4 + lrow) * kD + lcol);
  asm volatile("" ::: "memory");             // pin group {V0,K0} before {V1,K1}
  async_cp16(vg + (size_t)(s0 + r0 + 32 + lrow) * kD + lcol, v1b);
  async_cp16(vg + (size_t)(s0 + r0 + 36 + lrow) * kD + lcol, v1b + 256);
  kqB0 = *(const float4*)(kg + (size_t)(s0 + r0 + 32 + lrow) * kD + lcol);
  kqB1 = *(const float4*)(kg + (size_t)(s0 + r0 + 36 + lrow) * kD + lcol);
  asm volatile("" ::: "memory");             // pin prologue groups before round-0 issues
  mA0 = msk[r0 + lrow];      mA1 = msk[r0 + 4 + lrow];
  mB0 = msk[r0 + 32 + lrow]; mB1 = msk[r0 + 36 + lrow];

  int ts2 = s0 + r0 + 64;                    // tile t+2 global row base
  int to2 = r0 + 64;                         // tile t+2 mask offset

  // One round: consume K regs (relu/eps/mask + ksum + ds_write), issue tile
  // t+2 (2x global_load_lds for V, 2x float4 for K), counted vmcnt, inner MAC.
  // Compiler's own wait at the KQ consume drains exactly through group(t)
  // (V(t),K(t)), leaving groups t+1,t+2 in flight; the explicit vmcnt is the
  // compiler-independent guarantee that V(t) has landed in LDS.
#define PA_RND(KQ0, KQ1, M0, M1, WAITN, ISSUE)                                \
  {                                                                           \
    float4 kt0, kt1;                                                          \
    kt0.x = (fmaxf(KQ0.x, 0.f) + kEps) * M0;                                  \
    kt0.y = (fmaxf(KQ0.y, 0.f) + kEps) * M0;                                  \
    kt0.z = (fmaxf(KQ0.z, 0.f) + kEps) * M0;                                  \
    kt0.w = (fmaxf(KQ0.w, 0.f) + kEps) * M0;                                  \
    kt1.x = (fmaxf(KQ1.x, 0.f) + kEps) * M1;                                  \
    kt1.y = (fmaxf(KQ1.y, 0.f) + kEps) * M1;                                  \
    kt1.z = (fmaxf(KQ1.z, 0.f) + kEps) * M1;                                  \
    kt1.w = (fmaxf(KQ1.w, 0.f) + kEps) * M1;                                  \
    ksacc.x += kt0.x + kt1.x; ksacc.y += kt0.y + kt1.y;                       \
    ksacc.z += kt0.z + kt1.z; ksacc.w += kt0.w + kt1.w;                       \
    *(float4*)&ksT[lrow * 64 + lcol]       = kt0;                             \
    *(float4*)&ksT[(lrow + 4) * 64 + lcol] = kt1;                             \
    if (ISSUE) {                                                              \
      async_cp16(vg + (size_t)(ts2 + lrow) * kD + lcol, v2b);                 \
      async_cp16(vg + (size_t)(ts2 + 4 + lrow) * kD + lcol, v2b + 256);       \
      KQ0 = *(const float4*)(kg + (size_t)(ts2 + lrow) * kD + lcol);          \
      KQ1 = *(const float4*)(kg + (size_t)(ts2 + 4 + lrow) * kD + lcol);      \
      M0 = msk[to2 + lrow];  M1 = msk[to2 + 4 + lrow];                        \
      ts2 += 32; to2 += 32;                                                   \
    }                                                                         \
    asm volatile("s_waitcnt vmcnt(" #WAITN ")" ::: "memory");                 \
    _Pragma("unroll")                                                         \
    for (int ss = 0; ss < 8; ++ss) {                                          \
      const float4 kf0 = *(const float4*)&ksT[ss * 64 + 8 * ti];              \
      const float4 kf1 = *(const float4*)&ksT[ss * 64 + 8 * ti + 4];          \
      const float4 vf0 = *(const float4*)&v0b[ss * 64 + 8 * tj];              \
      const float4 vf1 = *(const float4*)&v0b[ss * 64 + 8 * tj + 4];          \
      const float ka[8] = {kf0.x, kf0.y, kf0.z, kf0.w,                        \
                           kf1.x, kf1.y, kf1.z, kf1.w};                       \
      const float va_[8] = {vf0.x, vf0.y, vf0.z, vf0.w,                       \
                            vf1.x, vf1.y, vf1.z, vf1.w};                      \
      _Pragma("unroll")                                                       \
      for (int i = 0; i < 8; ++i)                                             \
        _Pragma("unroll")                                                     \
        for (int j = 0; j < 8; ++j)                                           \
          acc[i][j] = fmaf(ka[i], va_[j], acc[i][j]);                         \
    }                                                                         \
    { float* rot_ = v0b; v0b = v1b; v1b = v2b; v2b = rot_; }                  \
  }

  // tiles is even (8 or 16): pairs keep reg-set parity static (rule: no
  // runtime-indexed register arrays). Steady rounds leave 8 VMEM in flight;
  // tail rounds drain 4 then 0.
  for (int t = 0; t < tiles - 2; t += 2) {
    PA_RND(kqA0, kqA1, mA0, mA1, 8, true)
    PA_RND(kqB0, kqB1, mB0, mB1, 8, true)
  }
  PA_RND(kqA0, kqA1, mA0, mA1, 4, false)
  PA_RND(kqB0, kqB1, mB0, mB1, 0, false)
#undef PA_RND

  // per-wave ksum fold: lanes sharing (lane&15) hold disjoint row partials
  ksacc.x += __shfl_xor(ksacc.x, 16); ksacc.x += __shfl_xor(ksacc.x, 32);
  ksacc.y += __shfl_xor(ksacc.y, 16); ksacc.y += __shfl_xor(ksacc.y, 32);
  ksacc.z += __shfl_xor(ksacc.z, 16); ksacc.z += __shfl_xor(ksacc.z, 32);
  ksacc.w += __shfl_xor(ksacc.w, 16); ksacc.w += __shfl_xor(ksacc.w, 32);
  if (lane < 16) *(float4*)&ksm[wid * 64 + 4 * lane] = ksacc;

  // block combine: wave w adds its 8x8 acc into smemV[0..4096) (permuted
  // layout: f4 slot j*64+lane = kv[8*(lane>>3)+(j>>1)][8*(lane&7)+4*(j&1)..])
#pragma unroll
  for (int w = 0; w < 4; ++w) {
    __syncthreads();
    if (wid == w) {
#pragma unroll
      for (int i = 0; i < 8; ++i)
#pragma unroll
        for (int jj = 0; jj < 2; ++jj) {
          const int j = i * 2 + jj;
          float4 o = make_float4(acc[i][jj * 4 + 0], acc[i][jj * 4 + 1],
                                 acc[i][jj * 4 + 2], acc[i][jj * 4 + 3]);
          float* p = &smemV[(size_t)(j * 64 + lane) * 4];
          if (w != 0) {
            const float4 prev = *(const float4*)p;
            o.x += prev.x; o.y += prev.y; o.z += prev.z; o.w += prev.w;
          }
          *(float4*)p = o;
        }
    }
  }
  __syncthreads();

  // cooperative coalesced store of the single block segment
  float* Pd = P + (size_t)blockIdx.x * SEG;
#pragma unroll
  for (int i = 0; i < 4; ++i) {
    const int idx = tid + 256 * i;
    *(float4*)&Pd[(size_t)idx * 4] = *(const float4*)&smemV[(size_t)idx * 4];
  }
  if (tid < kD)
    Pd[KVSZ + tid] = ksm[tid] + ksm[64 + tid] + ksm[128 + tid] + ksm[192 + tid];
}

// ---------------- Reduce: sum block partials, un-permute kv ----------------
__global__ __launch_bounds__(256)
void pa_reduce(const float* __restrict__ P, float* __restrict__ R, int nseg) {
  const int gid = blockIdx.x * 256 + threadIdx.x;
  if (gid >= kBH * F4PS) return;
  const int bh  = gid / F4PS;
  const int pos = gid - bh * F4PS;

  const float* base = P + (size_t)bh * nseg * SEG + (size_t)pos * 4;
  float ax = 0.f, ay = 0.f, az = 0.f, aw = 0.f;
  for (int c = 0; c < nseg; ++c) {
    const float4 t = *(const float4*)(base + (size_t)c * SEG);
    ax += t.x; ay += t.y; az += t.z; aw += t.w;
  }

  int dpos;
  if (pos < KVSZ / 4) {          // un-permute to natural [d][e]
    const int j  = pos >> 6, ln = pos & 63;
    const int d  = 8 * (ln >> 3) + (j >> 1);
    const int e4 = 2 * (ln & 7) + (j & 1);
    dpos = d * 16 + e4;
  } else {
    dpos = pos;                  // ksum already natural
  }
  *(float4*)&R[(size_t)bh * SEG + (size_t)dpos * 4] = make_float4(ax, ay, az, aw);
}

// ---------------- Pass 2: out = (q . kv) / (q . ksum) ----------------------
__global__ __launch_bounds__(256)
void pa_out(const float* __restrict__ query, const float* __restrict__ R,
            float* __restrict__ out) {
  __shared__ float ost[64 * 68];   // 64-row output staging, pad 68 (17 KiB)

  const int tid    = threadIdx.x;
  const int bh     = blockIdx.x >> 4;
  const int rowblk = blockIdx.x & 15;
  const int s      = rowblk * 256 + tid;

  const float* qrow = query + ((size_t)bh * kS + s) * kD;
  const float* Rb   = R + (size_t)bh * SEG;   // wave-uniform -> scalar loads

  float4 acc[16];
#pragma unroll
  for (int e = 0; e < 16; ++e) acc[e] = make_float4(0.f, 0.f, 0.f, 0.f);
  float den = 0.f;

#pragma unroll 4
  for (int d4 = 0; d4 < 16; ++d4) {
    const float4 qv = *(const float4*)(qrow + 4 * d4);
    const float qd[4] = {fmaxf(qv.x, 0.f) + kEps, fmaxf(qv.y, 0.f) + kEps,
                         fmaxf(qv.z, 0.f) + kEps, fmaxf(qv.w, 0.f) + kEps};
#pragma unroll
    for (int dd = 0; dd < 4; ++dd) {
      const int d = 4 * d4 + dd;
      den = fmaf(qd[dd], Rb[KVSZ + d], den);
      const float* kvr = Rb + d * 64;          // uniform row -> SGPR broadcast
#pragma unroll
      for (int e = 0; e < 16; ++e) {
        acc[e].x = fmaf(qd[dd], kvr[4 * e + 0], acc[e].x);
        acc[e].y = fmaf(qd[dd], kvr[4 * e + 1], acc[e].y);
        acc[e].z = fmaf(qd[dd], kvr[4 * e + 2], acc[e].z);
        acc[e].w = fmaf(qd[dd], kvr[4 * e + 3], acc[e].w);
      }
    }
  }

  const float inv = 1.0f / den;
#pragma unroll
  for (int e = 0; e < 16; ++e) {
    acc[e].x *= inv; acc[e].y *= inv; acc[e].z *= inv; acc[e].w *= inv;
  }

  // staged coalesced store: batch bb covers 64 rows written by wave bb
  float* ob = out + ((size_t)bh * kS + (size_t)rowblk * 256) * kD;
  const int wid = tid >> 6, l = tid & 63;
  for (int bb = 0; bb < 4; ++bb) {
    if (wid == bb) {
#pragma unroll
      for (int e = 0; e < 16; ++e) *(float4*)&ost[l * 68 + 4 * e] = acc[e];
    }
    __syncthreads();
#pragma unroll
    for (int jj = 0; jj < 4; ++jj) {
      const int g = tid + 256 * jj;
      const int r = g >> 4, c = g & 15;
      *(float4*)&ob[(size_t)(bb * 64 + r) * kD + 4 * c] =
          *(const float4*)&ost[r * 68 + 4 * c];
    }
    __syncthreads();
  }
}

extern "C" void kernel_launch(void* const* d_in, const int* in_sizes, int n_in,
                              void* d_out, int out_size, void* d_ws, size_t ws_size,
                              hipStream_t stream) {
  const float* query = (const float*)d_in[0];
  const float* key   = (const float*)d_in[1];
  const float* value = (const float*)d_in[2];
  const float* mask  = (const float*)d_in[3];
  float* outp = (float*)d_out;

  // CH1 = S-chunks per bh; ONE segment per block. Pick largest that fits ws.
  auto need = [](int ch1) -> size_t {
    return (size_t)(kBH * ch1 + kBH) * SEG * sizeof(float);
  };
  int CH1 = 8;                                  // 9.2 MB, known-safe floor
  if (ws_size >= need(16)) CH1 = 16;            // 18.1 MB, 1024 blocks (4/CU)

  float* P = (float*)d_ws;                      // kBH*CH1 segments
  float* R = P + (size_t)kBH * CH1 * SEG;       // kBH segments (natural layout)

  hipLaunchKernelGGL(pa_kv_partial, dim3(kBH * CH1), dim3(256), 0, stream,
                     key, value, mask, P, CH1);
  hipLaunchKernelGGL(pa_reduce, dim3((kBH * F4PS + 255) / 256), dim3(256), 0, stream,
                     P, R, CH1);
  hipLaunchKernelGGL(pa_out, dim3(kBH * 16), dim3(256), 0, stream,
                     query, R, outp);
}